// Round 1
// baseline (7131.623 us; speedup 1.0000x reference)
//
#include <hip/hip_runtime.h>
#include <cstdint>
#include <cstddef>

namespace {

constexpr int B = 8, S = 256, V = 32000, H = 1024;
constexpr int BS = B * S;  // 2048

typedef __attribute__((ext_vector_type(8))) short bf16x8;
typedef __attribute__((ext_vector_type(4))) float f32x4;

__device__ __forceinline__ unsigned short f2bf(float x) {
  union { float f; unsigned u; } v; v.f = x;
  unsigned r = v.u + 0x7fffu + ((v.u >> 16) & 1u);
  return (unsigned short)(r >> 16);
}

// ---------------- prep kernels ----------------

// fp32 -> bf16, 4 elems/thread, n % 1024 == 0
__global__ __launch_bounds__(256) void k_conv(const float* __restrict__ src,
                                              unsigned short* __restrict__ dst, int n) {
  int i = (blockIdx.x * 256 + threadIdx.x) * 4;
  if (i >= n) return;
  const float4 x = *(const float4*)(src + i);
  ushort4 o;
  o.x = f2bf(x.x); o.y = f2bf(x.y); o.z = f2bf(x.z); o.w = f2bf(x.w);
  *(ushort4*)(dst + i) = o;
}

// dst[j][k] = bf16(src[k][j]), 1024x1024
__global__ __launch_bounds__(256) void k_transconv(const float* __restrict__ src,
                                                   unsigned short* __restrict__ dst) {
  __shared__ float t[32][33];
  int x0 = blockIdx.x * 32, y0 = blockIdx.y * 32;
  int tx = threadIdx.x & 31, ty = threadIdx.x >> 5;
  for (int i = ty; i < 32; i += 8)
    t[i][tx] = src[(size_t)(y0 + i) * H + x0 + tx];
  __syncthreads();
  for (int i = ty; i < 32; i += 8)
    dst[(size_t)(x0 + i) * H + y0 + tx] = f2bf(t[tx][i]);
}

// Xbf[m][:] = bf16(E[tokens[m]][:])
__global__ __launch_bounds__(256) void k_gather(const int* __restrict__ tokens,
                                                const float* __restrict__ E,
                                                unsigned short* __restrict__ Xbf) {
  int m = blockIdx.x;
  int h = threadIdx.x * 4;
  int tok = tokens[m];
  const float4 x = *(const float4*)(E + (size_t)tok * H + h);
  ushort4 o; o.x = f2bf(x.x); o.y = f2bf(x.y); o.z = f2bf(x.z); o.w = f2bf(x.w);
  *(ushort4*)(Xbf + (size_t)m * H + h) = o;
}

// c1 = Wi1 @ bo0 + bi1 + bh1 ; bsum0 = bi0 + bh0 ; zero h-state rows + barrier
__global__ __launch_bounds__(256) void k_prep(const float* __restrict__ Wi1,
                                              const float* __restrict__ bo0,
                                              const float* __restrict__ bi0,
                                              const float* __restrict__ bi1,
                                              const float* __restrict__ bh0,
                                              const float* __restrict__ bh1,
                                              float* __restrict__ c1,
                                              float* __restrict__ bsum0,
                                              float* __restrict__ HS0,
                                              float* __restrict__ HS1,
                                              int* __restrict__ bar) {
  int i = blockIdx.x, t = threadIdx.x;
  int j = t * 4;
  float4 w = *(const float4*)(Wi1 + (size_t)i * H + j);
  float4 bv = *(const float4*)(bo0 + j);
  float a = w.x * bv.x + w.y * bv.y + w.z * bv.z + w.w * bv.w;
  #pragma unroll
  for (int o = 32; o; o >>= 1) a += __shfl_down(a, o, 64);
  __shared__ float red[4];
  if ((t & 63) == 0) red[t >> 6] = a;
  __syncthreads();
  if (t == 0) c1[i] = red[0] + red[1] + red[2] + red[3] + bi1[i] + bh1[i];
  if (t == 64) bsum0[i] = bi0[i] + bh0[i];
  if (i < 32) { HS0[i * 256 + t] = 0.f; HS1[i * 256 + t] = 0.f; }
  if (i == 0 && t == 128) *bar = 0;
}

// ---------------- bf16 MFMA GEMM: C[m,n] = sum_k A[m,k]*Bm[n,k] (+bias[n]) ----------------
// 128x128 tile, BK=64, global_load_lds 16B, XOR-swizzled LDS (2-way conflicts only).

__device__ __forceinline__ void async16(const unsigned short* g, unsigned short* l) {
  __builtin_amdgcn_global_load_lds(
      (const __attribute__((address_space(1))) unsigned int*)g,
      (__attribute__((address_space(3))) unsigned int*)l, 16, 0, 0);
}

template <int EPI>  // 0: +bias -> f32 ; 1: +bias -> bf16 ; 2: -> f32 (no bias)
__global__ __launch_bounds__(256) void gemm_bt(const unsigned short* __restrict__ A,
                                               const unsigned short* __restrict__ Bm,
                                               const float* __restrict__ bias,
                                               void* __restrict__ Cout,
                                               int Mrows, int N, int K) {
  __shared__ unsigned short sA[128 * 64];
  __shared__ unsigned short sB[128 * 64];
  const int bn = blockIdx.x, bm = blockIdx.y;
  const int tid = threadIdx.x;
  const int lane = tid & 63, wave = tid >> 6;
  const int wm = wave & 1, wn = wave >> 1;
  const int l15 = lane & 15, quad = lane >> 4;
  f32x4 acc[4][4] = {};

  const size_t row0 = (size_t)bm * 128, col0 = (size_t)bn * 128;

  int ldsbase[4], crow[4], ccol[4];
  #pragma unroll
  for (int i = 0; i < 4; ++i) {
    int g = i * 256 + wave * 64 + lane;   // granule 0..1023
    int r = g >> 3;
    int c = (g & 7) ^ (r & 7);            // source chunk for this granule
    crow[i] = r; ccol[i] = c * 8;
    ldsbase[i] = (i * 256 + wave * 64) * 8;  // wave-uniform LDS base (ushort idx)
  }

  const int kiters = K >> 6;
  for (int kt = 0; kt < kiters; ++kt) {
    __syncthreads();
    #pragma unroll
    for (int i = 0; i < 4; ++i) {
      const unsigned short* ga = A + (size_t)(row0 + crow[i]) * K + kt * 64 + ccol[i];
      async16(ga, &sA[ldsbase[i]]);
      const unsigned short* gb = Bm + (size_t)(col0 + crow[i]) * K + kt * 64 + ccol[i];
      async16(gb, &sB[ldsbase[i]]);
    }
    __syncthreads();  // drains vmcnt for global_load_lds
    #pragma unroll
    for (int kk = 0; kk < 2; ++kk) {
      bf16x8 af[4], bfr[4];
      #pragma unroll
      for (int sm = 0; sm < 4; ++sm) {
        int r = wm * 64 + sm * 16 + l15;
        int c = (kk * 4 + quad) ^ (r & 7);
        af[sm] = *(const bf16x8*)&sA[(r * 8 + c) * 8];
      }
      #pragma unroll
      for (int sn = 0; sn < 4; ++sn) {
        int r = wn * 64 + sn * 16 + l15;
        int c = (kk * 4 + quad) ^ (r & 7);
        bfr[sn] = *(const bf16x8*)&sB[(r * 8 + c) * 8];
      }
      #pragma unroll
      for (int sm = 0; sm < 4; ++sm)
        #pragma unroll
        for (int sn = 0; sn < 4; ++sn)
          acc[sm][sn] = __builtin_amdgcn_mfma_f32_16x16x32_bf16(af[sm], bfr[sn], acc[sm][sn], 0, 0, 0);
    }
  }

  // epilogue: C/D layout col=lane&15, row=quad*4+reg
  #pragma unroll
  for (int sn = 0; sn < 4; ++sn) {
    const size_t col = col0 + wn * 64 + sn * 16 + l15;
    float bv = 0.f;
    if (EPI != 2) bv = bias[col];
    #pragma unroll
    for (int sm = 0; sm < 4; ++sm) {
      const size_t rb = row0 + wm * 64 + sm * 16 + quad * 4;
      #pragma unroll
      for (int r = 0; r < 4; ++r) {
        float v = acc[sm][sn][r] + bv;
        size_t off = (rb + r) * (size_t)N + col;
        if (EPI == 1) ((unsigned short*)Cout)[off] = f2bf(v);
        else          ((float*)Cout)[off] = v;
      }
    }
  }
}

// ---------------- pipelined 2-layer recurrence ----------------
// tick k: hs0_k = tanh(A0_k + h0 Wh0^T)  and  hs1_{k-1} = tanh(hs0_{k-1} M^T + h1 Wh1^T + c1)
// HS0[t+1] = hs0_t, HS1[t+1-? ] convention: HS1[k] written at tick k holds hs1_{k-1}.
// 256 blocks (1/CU) x 256 threads; block owns 4 cols of each layer; one grid barrier/tick.

__device__ __forceinline__ void gbar(int* bar, int target) {
  __syncthreads();
  if (threadIdx.x == 0) {
    __threadfence();  // agent release: flush to coherence point (cross-XCD)
    __hip_atomic_fetch_add(bar, 1, __ATOMIC_RELAXED, __HIP_MEMORY_SCOPE_AGENT);
    while (__hip_atomic_load(bar, __ATOMIC_RELAXED, __HIP_MEMORY_SCOPE_AGENT) < target) {
      __builtin_amdgcn_s_sleep(2);
    }
    __threadfence();  // agent acquire: invalidate stale cached lines
  }
  __syncthreads();
}

__global__ __launch_bounds__(256) void rnn_scan(const float* __restrict__ A0,
                                                const float* __restrict__ Wh0,
                                                const float* __restrict__ Mm,
                                                const float* __restrict__ Wh1,
                                                const float* __restrict__ c1,
                                                float* __restrict__ HS0,
                                                float* __restrict__ HS1,
                                                unsigned short* __restrict__ HS1bf,
                                                int* __restrict__ bar) {
  const int tid = threadIdx.x;
  const int blk = blockIdx.x;
  const int b = tid & 7;
  const int js = tid >> 3;  // 0..31 -> K-slice of 32
  const int col0 = blk * 4;
  const int joff = js * 32;
  __shared__ float red[8][8][33];  // [4 L0 cols + 4 L1 cols][b][js]

  for (int k = 0; k <= S; ++k) {
    float4 h0v[8];
    float4 h1v[8] = {};
    const float* h0p = HS0 + (size_t)k * (B * H) + b * H + joff;  // hs0_{k-1}
    #pragma unroll
    for (int i = 0; i < 8; ++i) h0v[i] = *(const float4*)(h0p + i * 4);
    if (k >= 1) {
      const float* h1p = HS1 + (size_t)(k - 1) * (B * H) + b * H + joff;  // hs1_{k-2}
      #pragma unroll
      for (int i = 0; i < 8; ++i) h1v[i] = *(const float4*)(h1p + i * 4);
    }
    #pragma unroll
    for (int c = 0; c < 4; ++c) {
      const int col = col0 + c;
      if (k < S) {
        const float* w = Wh0 + (size_t)col * H + joff;
        float a = 0.f;
        #pragma unroll
        for (int i = 0; i < 8; ++i) {
          float4 wv = *(const float4*)(w + i * 4);
          a += h0v[i].x * wv.x + h0v[i].y * wv.y + h0v[i].z * wv.z + h0v[i].w * wv.w;
        }
        red[c][b][js] = a;
      }
      if (k >= 1) {
        const float* wm_ = Mm + (size_t)col * H + joff;
        const float* w1_ = Wh1 + (size_t)col * H + joff;
        float a = 0.f;
        #pragma unroll
        for (int i = 0; i < 8; ++i) {
          float4 mv = *(const float4*)(wm_ + i * 4);
          float4 wv = *(const float4*)(w1_ + i * 4);
          a += h0v[i].x * mv.x + h0v[i].y * mv.y + h0v[i].z * mv.z + h0v[i].w * mv.w;
          a += h1v[i].x * wv.x + h1v[i].y * wv.y + h1v[i].z * wv.z + h1v[i].w * wv.w;
        }
        red[4 + c][b][js] = a;
      }
    }
    __syncthreads();
    if (tid < 64) {
      const int cc = tid >> 3, bb = tid & 7;
      float s = 0.f;
      #pragma unroll
      for (int j = 0; j < 32; ++j) s += red[cc][bb][j];
      if (cc < 4) {
        if (k < S) {
          const int col = col0 + cc;
          float v = tanhf(A0[(size_t)(bb * S + k) * H + col] + s);
          HS0[(size_t)(k + 1) * (B * H) + bb * H + col] = v;
        }
      } else {
        if (k >= 1) {
          const int col = col0 + cc - 4;
          float v = tanhf(c1[col] + s);
          HS1[(size_t)k * (B * H) + bb * H + col] = v;
          HS1bf[(size_t)(bb * S + (k - 1)) * H + col] = f2bf(v);
        }
      }
    }
    if (k == S) break;
    gbar(bar, 256 * (k + 1));
  }
}

// ---------------- softmax ----------------

__global__ __launch_bounds__(256) void k_rowred(const float* __restrict__ Lg,
                                                float* __restrict__ rmax,
                                                float* __restrict__ rinv) {
  const int r = blockIdx.x;
  const float* p = Lg + (size_t)r * V;
  float m = -3.4e38f;
  for (int v = threadIdx.x * 4; v < V; v += 1024) {
    float4 x = *(const float4*)(p + v);
    m = fmaxf(m, fmaxf(fmaxf(x.x, x.y), fmaxf(x.z, x.w)));
  }
  #pragma unroll
  for (int o = 32; o; o >>= 1) m = fmaxf(m, __shfl_down(m, o, 64));
  __shared__ float sm_[4];
  __shared__ float bm;
  if ((threadIdx.x & 63) == 0) sm_[threadIdx.x >> 6] = m;
  __syncthreads();
  if (threadIdx.x == 0) bm = fmaxf(fmaxf(sm_[0], sm_[1]), fmaxf(sm_[2], sm_[3]));
  __syncthreads();
  m = bm;
  float s = 0.f;
  for (int v = threadIdx.x * 4; v < V; v += 1024) {
    float4 x = *(const float4*)(p + v);
    s += __expf(x.x - m) + __expf(x.y - m) + __expf(x.z - m) + __expf(x.w - m);
  }
  #pragma unroll
  for (int o = 32; o; o >>= 1) s += __shfl_down(s, o, 64);
  __syncthreads();
  if ((threadIdx.x & 63) == 0) sm_[threadIdx.x >> 6] = s;
  __syncthreads();
  if (threadIdx.x == 0) {
    rmax[r] = m;
    rinv[r] = 1.f / (sm_[0] + sm_[1] + sm_[2] + sm_[3]);
  }
}

__global__ __launch_bounds__(256) void k_norm(float* __restrict__ Lg,
                                              const float* __restrict__ rmax,
                                              const float* __restrict__ rinv) {
  const int r = blockIdx.y;
  const int v = blockIdx.x * 1024 + threadIdx.x * 4;
  if (v >= V) return;
  const float m = rmax[r], s = rinv[r];
  float* p = Lg + (size_t)r * V + v;
  float4 x = *(const float4*)p;
  x.x = __expf(x.x - m) * s;
  x.y = __expf(x.y - m) * s;
  x.z = __expf(x.z - m) * s;
  x.w = __expf(x.w - m) * s;
  *(float4*)p = x;
}

}  // namespace

extern "C" void kernel_launch(void* const* d_in, const int* in_sizes, int n_in,
                              void* d_out, int out_size, void* d_ws, size_t ws_size,
                              hipStream_t stream) {
  (void)in_sizes; (void)n_in; (void)out_size; (void)ws_size;
  const int*   tokens = (const int*)d_in[0];
  const float* E   = (const float*)d_in[1];
  const float* Wi  = (const float*)d_in[2];
  const float* bi  = (const float*)d_in[3];
  const float* Wh  = (const float*)d_in[4];
  const float* bh  = (const float*)d_in[5];
  const float* Wo  = (const float*)d_in[6];
  const float* bo  = (const float*)d_in[7];
  float* out = (float*)d_out;

  char* w = (char*)d_ws;
  auto alloc = [&](size_t bytes) { char* p = w; w += (bytes + 255) & ~(size_t)255; return p; };
  unsigned short* Ebf    = (unsigned short*)alloc((size_t)V * H * 2);
  unsigned short* Xbf    = (unsigned short*)alloc((size_t)BS * H * 2);
  unsigned short* Wi0bf  = (unsigned short*)alloc((size_t)H * H * 2);
  unsigned short* Wi1bf  = (unsigned short*)alloc((size_t)H * H * 2);
  unsigned short* Wo1bf  = (unsigned short*)alloc((size_t)H * H * 2);
  unsigned short* Wo0Tbf = (unsigned short*)alloc((size_t)H * H * 2);
  float* Mmat  = (float*)alloc((size_t)H * H * 4);
  float* A0f   = (float*)alloc((size_t)BS * H * 4);
  float* HS0   = (float*)alloc((size_t)(S + 1) * B * H * 4);
  float* HS1   = (float*)alloc((size_t)(S + 1) * B * H * 4);
  unsigned short* HS1bf = (unsigned short*)alloc((size_t)BS * H * 2);
  unsigned short* OUTbf = (unsigned short*)alloc((size_t)BS * H * 2);
  float* bsum0 = (float*)alloc(H * 4);
  float* c1v   = (float*)alloc(H * 4);
  float* rmax  = (float*)alloc(BS * 4);
  float* rinv  = (float*)alloc(BS * 4);
  int*   bar   = (int*)alloc(256);

  const float* Wi0 = Wi;               const float* Wi1 = Wi + (size_t)H * H;
  const float* Wh0 = Wh;               const float* Wh1 = Wh + (size_t)H * H;
  const float* Wo0 = Wo;               const float* Wo1 = Wo + (size_t)H * H;
  const float* bi0 = bi;  const float* bi1 = bi + H;
  const float* bh0 = bh;  const float* bh1 = bh + H;
  const float* bo0 = bo;  const float* bo1 = bo + H;

  // --- prep / conversions ---
  k_conv<<<dim3((V * H) / 1024), dim3(256), 0, stream>>>(E, Ebf, V * H);
  k_conv<<<dim3((H * H) / 1024), dim3(256), 0, stream>>>(Wi0, Wi0bf, H * H);
  k_conv<<<dim3((H * H) / 1024), dim3(256), 0, stream>>>(Wi1, Wi1bf, H * H);
  k_conv<<<dim3((H * H) / 1024), dim3(256), 0, stream>>>(Wo1, Wo1bf, H * H);
  k_transconv<<<dim3(32, 32), dim3(256), 0, stream>>>(Wo0, Wo0Tbf);
  k_gather<<<dim3(BS), dim3(256), 0, stream>>>(tokens, E, Xbf);
  k_prep<<<dim3(H), dim3(256), 0, stream>>>(Wi1, bo0, bi0, bi1, bh0, bh1,
                                            c1v, bsum0, HS0, HS1, bar);

  // M = Wi1 @ Wo0  (fp32 out, bf16 MFMA)
  gemm_bt<2><<<dim3(8, 8), dim3(256), 0, stream>>>(Wi1bf, Wo0Tbf, nullptr, Mmat, H, H, H);
  // A0 = X @ Wi0^T + (bi0 + bh0)
  gemm_bt<0><<<dim3(8, 16), dim3(256), 0, stream>>>(Xbf, Wi0bf, bsum0, A0f, BS, H, H);

  // sequential scan (persistent, 1 block/CU, custom grid barrier)
  rnn_scan<<<dim3(256), dim3(256), 0, stream>>>(A0f, Wh0, Mmat, Wh1, c1v,
                                                HS0, HS1, HS1bf, bar);

  // OUT = HS1 @ Wo1^T + bo1  (bf16 out)
  gemm_bt<1><<<dim3(8, 16), dim3(256), 0, stream>>>(HS1bf, Wo1bf, bo1, OUTbf, BS, H, H);
  // logits = OUT @ E^T  (fp32 into d_out)
  gemm_bt<2><<<dim3(250, 16), dim3(256), 0, stream>>>(OUTbf, Ebf, nullptr, out, BS, V, H);

  // softmax over V, in place on d_out
  k_rowred<<<dim3(BS), dim3(256), 0, stream>>>(out, rmax, rinv);
  k_norm<<<dim3(32, BS), dim3(256), 0, stream>>>(out, rmax, rinv);
}

// Round 2
// 5035.829 us; speedup vs baseline: 1.4162x; 1.4162x over previous
//
#include <hip/hip_runtime.h>
#include <cstdint>
#include <cstddef>

namespace {

constexpr int B = 8, S = 256, V = 32000, H = 1024;
constexpr int BS = B * S;  // 2048
constexpr int NBLK = 128;  // rnn_scan grid (persistent, 1 block/CU guaranteed)
constexpr int CPL = H / NBLK;  // cols per layer per block = 8

typedef __attribute__((ext_vector_type(8))) short bf16x8;
typedef __attribute__((ext_vector_type(4))) float f32x4;

__device__ __forceinline__ unsigned short f2bf(float x) {
  union { float f; unsigned u; } v; v.f = x;
  unsigned r = v.u + 0x7fffu + ((v.u >> 16) & 1u);
  return (unsigned short)(r >> 16);
}

// ---------------- prep kernels ----------------

__global__ __launch_bounds__(256) void k_conv(const float* __restrict__ src,
                                              unsigned short* __restrict__ dst, int n) {
  int i = (blockIdx.x * 256 + threadIdx.x) * 4;
  if (i >= n) return;
  const float4 x = *(const float4*)(src + i);
  ushort4 o;
  o.x = f2bf(x.x); o.y = f2bf(x.y); o.z = f2bf(x.z); o.w = f2bf(x.w);
  *(ushort4*)(dst + i) = o;
}

__global__ __launch_bounds__(256) void k_transconv(const float* __restrict__ src,
                                                   unsigned short* __restrict__ dst) {
  __shared__ float t[32][33];
  int x0 = blockIdx.x * 32, y0 = blockIdx.y * 32;
  int tx = threadIdx.x & 31, ty = threadIdx.x >> 5;
  for (int i = ty; i < 32; i += 8)
    t[i][tx] = src[(size_t)(y0 + i) * H + x0 + tx];
  __syncthreads();
  for (int i = ty; i < 32; i += 8)
    dst[(size_t)(x0 + i) * H + y0 + tx] = f2bf(t[tx][i]);
}

__global__ __launch_bounds__(256) void k_gather(const int* __restrict__ tokens,
                                                const float* __restrict__ E,
                                                unsigned short* __restrict__ Xbf) {
  int m = blockIdx.x;
  int h = threadIdx.x * 4;
  int tok = tokens[m];
  const float4 x = *(const float4*)(E + (size_t)tok * H + h);
  ushort4 o; o.x = f2bf(x.x); o.y = f2bf(x.y); o.z = f2bf(x.z); o.w = f2bf(x.w);
  *(ushort4*)(Xbf + (size_t)m * H + h) = o;
}

__global__ __launch_bounds__(256) void k_prep(const float* __restrict__ Wi1,
                                              const float* __restrict__ bo0,
                                              const float* __restrict__ bi0,
                                              const float* __restrict__ bi1,
                                              const float* __restrict__ bh0,
                                              const float* __restrict__ bh1,
                                              float* __restrict__ c1,
                                              float* __restrict__ bsum0,
                                              float* __restrict__ HS0,
                                              float* __restrict__ HS1,
                                              int* __restrict__ bar) {
  int i = blockIdx.x, t = threadIdx.x;
  int j = t * 4;
  float4 w = *(const float4*)(Wi1 + (size_t)i * H + j);
  float4 bv = *(const float4*)(bo0 + j);
  float a = w.x * bv.x + w.y * bv.y + w.z * bv.z + w.w * bv.w;
  #pragma unroll
  for (int o = 32; o; o >>= 1) a += __shfl_down(a, o, 64);
  __shared__ float red[4];
  if ((t & 63) == 0) red[t >> 6] = a;
  __syncthreads();
  if (t == 0) c1[i] = red[0] + red[1] + red[2] + red[3] + bi1[i] + bh1[i];
  if (t == 64) bsum0[i] = bi0[i] + bh0[i];
  if (i < 32) { HS0[i * 256 + t] = 0.f; HS1[i * 256 + t] = 0.f; }
  if (i == 0 && t == 128) *bar = 0;
}

// ---------------- bf16 MFMA GEMM (unchanged from R1) ----------------

__device__ __forceinline__ void async16(const unsigned short* g, unsigned short* l) {
  __builtin_amdgcn_global_load_lds(
      (const __attribute__((address_space(1))) unsigned int*)g,
      (__attribute__((address_space(3))) unsigned int*)l, 16, 0, 0);
}

template <int EPI>  // 0: +bias -> f32 ; 1: +bias -> bf16 ; 2: -> f32 (no bias)
__global__ __launch_bounds__(256) void gemm_bt(const unsigned short* __restrict__ A,
                                               const unsigned short* __restrict__ Bm,
                                               const float* __restrict__ bias,
                                               void* __restrict__ Cout,
                                               int Mrows, int N, int K) {
  __shared__ unsigned short sA[128 * 64];
  __shared__ unsigned short sB[128 * 64];
  const int bn = blockIdx.x, bm = blockIdx.y;
  const int tid = threadIdx.x;
  const int lane = tid & 63, wave = tid >> 6;
  const int wm = wave & 1, wn = wave >> 1;
  const int l15 = lane & 15, quad = lane >> 4;
  f32x4 acc[4][4] = {};

  const size_t row0 = (size_t)bm * 128, col0 = (size_t)bn * 128;

  int ldsbase[4], crow[4], ccol[4];
  #pragma unroll
  for (int i = 0; i < 4; ++i) {
    int g = i * 256 + wave * 64 + lane;
    int r = g >> 3;
    int c = (g & 7) ^ (r & 7);
    crow[i] = r; ccol[i] = c * 8;
    ldsbase[i] = (i * 256 + wave * 64) * 8;
  }

  const int kiters = K >> 6;
  for (int kt = 0; kt < kiters; ++kt) {
    __syncthreads();
    #pragma unroll
    for (int i = 0; i < 4; ++i) {
      const unsigned short* ga = A + (size_t)(row0 + crow[i]) * K + kt * 64 + ccol[i];
      async16(ga, &sA[ldsbase[i]]);
      const unsigned short* gb = Bm + (size_t)(col0 + crow[i]) * K + kt * 64 + ccol[i];
      async16(gb, &sB[ldsbase[i]]);
    }
    __syncthreads();
    #pragma unroll
    for (int kk = 0; kk < 2; ++kk) {
      bf16x8 af[4], bfr[4];
      #pragma unroll
      for (int sm = 0; sm < 4; ++sm) {
        int r = wm * 64 + sm * 16 + l15;
        int c = (kk * 4 + quad) ^ (r & 7);
        af[sm] = *(const bf16x8*)&sA[(r * 8 + c) * 8];
      }
      #pragma unroll
      for (int sn = 0; sn < 4; ++sn) {
        int r = wn * 64 + sn * 16 + l15;
        int c = (kk * 4 + quad) ^ (r & 7);
        bfr[sn] = *(const bf16x8*)&sB[(r * 8 + c) * 8];
      }
      #pragma unroll
      for (int sm = 0; sm < 4; ++sm)
        #pragma unroll
        for (int sn = 0; sn < 4; ++sn)
          acc[sm][sn] = __builtin_amdgcn_mfma_f32_16x16x32_bf16(af[sm], bfr[sn], acc[sm][sn], 0, 0, 0);
    }
  }

  #pragma unroll
  for (int sn = 0; sn < 4; ++sn) {
    const size_t col = col0 + wn * 64 + sn * 16 + l15;
    float bv = 0.f;
    if (EPI != 2) bv = bias[col];
    #pragma unroll
    for (int sm = 0; sm < 4; ++sm) {
      const size_t rb = row0 + wm * 64 + sm * 16 + quad * 4;
      #pragma unroll
      for (int r = 0; r < 4; ++r) {
        float v = acc[sm][sn][r] + bv;
        size_t off = (rb + r) * (size_t)N + col;
        if (EPI == 1) ((unsigned short*)Cout)[off] = f2bf(v);
        else          ((float*)Cout)[off] = v;
      }
    }
  }
}

// ---------------- pipelined 2-layer recurrence, v2 ----------------
// NO fences. h-state exchanged via agent-scope cache-bypassing atomics;
// weights stay warm in L1/L2 across all ticks. Barrier: monotone counter,
// relaxed atomics; __syncthreads' vmcnt(0) drain before s_barrier provides
// the release ordering for the finisher stores.

__device__ __forceinline__ void gbar(int* bar, int target) {
  __syncthreads();  // drains vmcnt(0): all waves' h-stores reached MALL
  if (threadIdx.x == 0) {
    __hip_atomic_fetch_add(bar, 1, __ATOMIC_RELAXED, __HIP_MEMORY_SCOPE_AGENT);
    while (__hip_atomic_load(bar, __ATOMIC_RELAXED, __HIP_MEMORY_SCOPE_AGENT) < target)
      __builtin_amdgcn_s_sleep(1);
  }
  __syncthreads();
}

__global__ __launch_bounds__(256) void rnn_scan(const float* __restrict__ A0,
                                                const float* __restrict__ Wh0,
                                                const float* __restrict__ Mm,
                                                const float* __restrict__ Wh1,
                                                const float* __restrict__ c1,
                                                float* __restrict__ HS0,
                                                float* __restrict__ HS1,
                                                unsigned short* __restrict__ HS1bf,
                                                int* __restrict__ bar) {
  __shared__ float lh0[B * H];          // 32 KB  hs0_{k-1}, [b][h]
  __shared__ float lh1[B * H];          // 32 KB  hs1_{k-2}, [b][h]
  __shared__ float red[2 * CPL][8][33]; // 16.9 KB
  const int tid = threadIdx.x;
  const int blk = blockIdx.x;
  const int b = tid & 7;
  const int js = tid >> 3;            // 0..31, K-slice of 32
  const int joff = js * 32;
  const int col0 = blk * CPL;
  const int cc = tid >> 3, bb = tid & 7;  // finisher mapping (tid < 128)
  unsigned long long* l0u = (unsigned long long*)lh0;
  unsigned long long* l1u = (unsigned long long*)lh1;

  float c1v = 0.f;
  if (tid < 128 && cc >= CPL) c1v = c1[col0 + cc - CPL];

  for (int k = 0; k <= S; ++k) {
    // prefetch finisher epilogue operand
    float a0 = 0.f;
    if (k < S && tid < 128 && cc < CPL)
      a0 = A0[(size_t)(bb * S + k) * H + col0 + cc];

    // stage h broadcast into LDS: coalesced 8B cache-bypassing loads
    const unsigned long long* g0 = (const unsigned long long*)(HS0 + (size_t)k * (B * H));
    #pragma unroll
    for (int i = 0; i < 16; ++i)
      l0u[i * 256 + tid] =
          __hip_atomic_load(g0 + i * 256 + tid, __ATOMIC_RELAXED, __HIP_MEMORY_SCOPE_AGENT);
    if (k >= 1) {
      const unsigned long long* g1 = (const unsigned long long*)(HS1 + (size_t)(k - 1) * (B * H));
      #pragma unroll
      for (int i = 0; i < 16; ++i)
        l1u[i * 256 + tid] =
            __hip_atomic_load(g1 + i * 256 + tid, __ATOMIC_RELAXED, __HIP_MEMORY_SCOPE_AGENT);
    }
    __syncthreads();

    float4 h0v[8], h1v[8];
    #pragma unroll
    for (int i = 0; i < 8; ++i) h0v[i] = *(const float4*)&lh0[b * H + joff + i * 4];
    if (k >= 1) {
      #pragma unroll
      for (int i = 0; i < 8; ++i) h1v[i] = *(const float4*)&lh1[b * H + joff + i * 4];
    }

    #pragma unroll
    for (int c = 0; c < CPL; ++c) {
      const int col = col0 + c;
      if (k < S) {
        const float* w = Wh0 + (size_t)col * H + joff;
        float a = 0.f;
        #pragma unroll
        for (int i = 0; i < 8; ++i) {
          float4 wv = *(const float4*)(w + i * 4);
          a += h0v[i].x * wv.x + h0v[i].y * wv.y + h0v[i].z * wv.z + h0v[i].w * wv.w;
        }
        red[c][b][js] = a;
      }
      if (k >= 1) {
        const float* wm_ = Mm + (size_t)col * H + joff;
        const float* w1_ = Wh1 + (size_t)col * H + joff;
        float a = 0.f;
        #pragma unroll
        for (int i = 0; i < 8; ++i) {
          float4 mv = *(const float4*)(wm_ + i * 4);
          float4 wv = *(const float4*)(w1_ + i * 4);
          a += h0v[i].x * mv.x + h0v[i].y * mv.y + h0v[i].z * mv.z + h0v[i].w * mv.w;
          a += h1v[i].x * wv.x + h1v[i].y * wv.y + h1v[i].z * wv.z + h1v[i].w * wv.w;
        }
        red[CPL + c][b][js] = a;
      }
    }
    __syncthreads();

    if (tid < 128) {
      float s = 0.f;
      #pragma unroll
      for (int j = 0; j < 32; ++j) s += red[cc][bb][j];
      if (cc < CPL) {
        if (k < S) {
          const int col = col0 + cc;
          float v = tanhf(a0 + s);
          __hip_atomic_store(HS0 + (size_t)(k + 1) * (B * H) + bb * H + col, v,
                             __ATOMIC_RELAXED, __HIP_MEMORY_SCOPE_AGENT);
        }
      } else {
        if (k >= 1) {
          const int col = col0 + cc - CPL;
          float v = tanhf(c1v + s);
          __hip_atomic_store(HS1 + (size_t)k * (B * H) + bb * H + col, v,
                             __ATOMIC_RELAXED, __HIP_MEMORY_SCOPE_AGENT);
          HS1bf[(size_t)(bb * S + (k - 1)) * H + col] = f2bf(v);  // regular store: read post-kernel
        }
      }
    }
    if (k == S) break;
    gbar(bar, NBLK * (k + 1));
  }
}

// ---------------- softmax ----------------

__global__ __launch_bounds__(256) void k_rowred(const float* __restrict__ Lg,
                                                float* __restrict__ rmax,
                                                float* __restrict__ rinv) {
  const int r = blockIdx.x;
  const float* p = Lg + (size_t)r * V;
  float m = -3.4e38f;
  for (int v = threadIdx.x * 4; v < V; v += 1024) {
    float4 x = *(const float4*)(p + v);
    m = fmaxf(m, fmaxf(fmaxf(x.x, x.y), fmaxf(x.z, x.w)));
  }
  #pragma unroll
  for (int o = 32; o; o >>= 1) m = fmaxf(m, __shfl_down(m, o, 64));
  __shared__ float sm_[4];
  __shared__ float bm;
  if ((threadIdx.x & 63) == 0) sm_[threadIdx.x >> 6] = m;
  __syncthreads();
  if (threadIdx.x == 0) bm = fmaxf(fmaxf(sm_[0], sm_[1]), fmaxf(sm_[2], sm_[3]));
  __syncthreads();
  m = bm;
  float s = 0.f;
  for (int v = threadIdx.x * 4; v < V; v += 1024) {
    float4 x = *(const float4*)(p + v);
    s += __expf(x.x - m) + __expf(x.y - m) + __expf(x.z - m) + __expf(x.w - m);
  }
  #pragma unroll
  for (int o = 32; o; o >>= 1) s += __shfl_down(s, o, 64);
  __syncthreads();
  if ((threadIdx.x & 63) == 0) sm_[threadIdx.x >> 6] = s;
  __syncthreads();
  if (threadIdx.x == 0) {
    rmax[r] = m;
    rinv[r] = 1.f / (sm_[0] + sm_[1] + sm_[2] + sm_[3]);
  }
}

__global__ __launch_bounds__(256) void k_norm(float* __restrict__ Lg,
                                              const float* __restrict__ rmax,
                                              const float* __restrict__ rinv) {
  const int r = blockIdx.y;
  const int v = blockIdx.x * 1024 + threadIdx.x * 4;
  if (v >= V) return;
  const float m = rmax[r], s = rinv[r];
  float* p = Lg + (size_t)r * V + v;
  float4 x = *(const float4*)p;
  x.x = __expf(x.x - m) * s;
  x.y = __expf(x.y - m) * s;
  x.z = __expf(x.z - m) * s;
  x.w = __expf(x.w - m) * s;
  *(float4*)p = x;
}

}  // namespace

extern "C" void kernel_launch(void* const* d_in, const int* in_sizes, int n_in,
                              void* d_out, int out_size, void* d_ws, size_t ws_size,
                              hipStream_t stream) {
  (void)in_sizes; (void)n_in; (void)out_size; (void)ws_size;
  const int*   tokens = (const int*)d_in[0];
  const float* E   = (const float*)d_in[1];
  const float* Wi  = (const float*)d_in[2];
  const float* bi  = (const float*)d_in[3];
  const float* Wh  = (const float*)d_in[4];
  const float* bh  = (const float*)d_in[5];
  const float* Wo  = (const float*)d_in[6];
  const float* bo  = (const float*)d_in[7];
  float* out = (float*)d_out;

  char* w = (char*)d_ws;
  auto alloc = [&](size_t bytes) { char* p = w; w += (bytes + 255) & ~(size_t)255; return p; };
  unsigned short* Ebf    = (unsigned short*)alloc((size_t)V * H * 2);
  unsigned short* Xbf    = (unsigned short*)alloc((size_t)BS * H * 2);
  unsigned short* Wi0bf  = (unsigned short*)alloc((size_t)H * H * 2);
  unsigned short* Wi1bf  = (unsigned short*)alloc((size_t)H * H * 2);
  unsigned short* Wo1bf  = (unsigned short*)alloc((size_t)H * H * 2);
  unsigned short* Wo0Tbf = (unsigned short*)alloc((size_t)H * H * 2);
  float* Mmat  = (float*)alloc((size_t)H * H * 4);
  float* A0f   = (float*)alloc((size_t)BS * H * 4);
  float* HS0   = (float*)alloc((size_t)(S + 1) * B * H * 4);
  float* HS1   = (float*)alloc((size_t)(S + 1) * B * H * 4);
  unsigned short* HS1bf = (unsigned short*)alloc((size_t)BS * H * 2);
  unsigned short* OUTbf = (unsigned short*)alloc((size_t)BS * H * 2);
  float* bsum0 = (float*)alloc(H * 4);
  float* c1v   = (float*)alloc(H * 4);
  float* rmax  = (float*)alloc(BS * 4);
  float* rinv  = (float*)alloc(BS * 4);
  int*   bar   = (int*)alloc(256);

  const float* Wi0 = Wi;               const float* Wi1 = Wi + (size_t)H * H;
  const float* Wh0 = Wh;               const float* Wh1 = Wh + (size_t)H * H;
  const float* Wo0 = Wo;               const float* Wo1 = Wo + (size_t)H * H;
  const float* bi0 = bi;  const float* bi1 = bi + H;
  const float* bh0 = bh;  const float* bh1 = bh + H;
  const float* bo0 = bo;  const float* bo1 = bo + H;

  k_conv<<<dim3((V * H) / 1024), dim3(256), 0, stream>>>(E, Ebf, V * H);
  k_conv<<<dim3((H * H) / 1024), dim3(256), 0, stream>>>(Wi0, Wi0bf, H * H);
  k_conv<<<dim3((H * H) / 1024), dim3(256), 0, stream>>>(Wi1, Wi1bf, H * H);
  k_conv<<<dim3((H * H) / 1024), dim3(256), 0, stream>>>(Wo1, Wo1bf, H * H);
  k_transconv<<<dim3(32, 32), dim3(256), 0, stream>>>(Wo0, Wo0Tbf);
  k_gather<<<dim3(BS), dim3(256), 0, stream>>>(tokens, E, Xbf);
  k_prep<<<dim3(H), dim3(256), 0, stream>>>(Wi1, bo0, bi0, bi1, bh0, bh1,
                                            c1v, bsum0, HS0, HS1, bar);

  gemm_bt<2><<<dim3(8, 8), dim3(256), 0, stream>>>(Wi1bf, Wo0Tbf, nullptr, Mmat, H, H, H);
  gemm_bt<0><<<dim3(8, 16), dim3(256), 0, stream>>>(Xbf, Wi0bf, bsum0, A0f, BS, H, H);

  rnn_scan<<<dim3(NBLK), dim3(256), 0, stream>>>(A0f, Wh0, Mmat, Wh1, c1v,
                                                 HS0, HS1, HS1bf, bar);

  gemm_bt<1><<<dim3(8, 16), dim3(256), 0, stream>>>(HS1bf, Wo1bf, bo1, OUTbf, BS, H, H);
  gemm_bt<2><<<dim3(250, 16), dim3(256), 0, stream>>>(OUTbf, Ebf, nullptr, out, BS, V, H);

  k_rowred<<<dim3(BS), dim3(256), 0, stream>>>(out, rmax, rinv);
  k_norm<<<dim3(32, BS), dim3(256), 0, stream>>>(out, rmax, rinv);
}